// Round 3
// baseline (3194.962 us; speedup 1.0000x reference)
//
#include <hip/hip_runtime.h>

#define NN 50000
#define NE 800000
#define LEAKY 0.2f

// ---------------------------------------------------------------- zero
__global__ void zero_ints(int* __restrict__ p, int n) {
  int i = blockIdx.x * blockDim.x + threadIdx.x;
  int s = gridDim.x * blockDim.x;
  for (; i < n; i += s) p[i] = 0;
}

// ---------------------------------------------------------------- degrees
__global__ void deg_kernel(const int* __restrict__ s1, const int* __restrict__ d1,
                           const int* __restrict__ s2, const int* __restrict__ d2,
                           int* od1, int* id1, int* od2, int* id2) {
  int i = blockIdx.x * blockDim.x + threadIdx.x;
  int st = gridDim.x * blockDim.x;
  for (int e = i; e < NE; e += st) {
    int a = s1[e], b = d1[e], c = s2[e], d = d2[e];
    atomicAdd(&od1[a], 1);
    atomicAdd(&id1[b], 1);
    atomicAdd(&od2[c], 1);
    atomicAdd(&id2[d], 1);
  }
}

__global__ void scale_kernel(const int* __restrict__ od1, const int* __restrict__ id1,
                             const int* __restrict__ od2, const int* __restrict__ id2,
                             float* io1, float* ii1, float* io2, float* ii2) {
  int i = blockIdx.x * blockDim.x + threadIdx.x;
  if (i < NN) {
    io1[i] = rsqrtf((float)(od1[i] > 0 ? od1[i] : 1));
    ii1[i] = rsqrtf((float)(id1[i] > 0 ? id1[i] : 1));
    io2[i] = rsqrtf((float)(od2[i] > 0 ? od2[i] : 1));
    ii2[i] = rsqrtf((float)(id2[i] > 0 ? id2[i] : 1));
  }
}

// ---------------------------------------------------------------- scan (row_ptr)
// 2 blocks of 1024: block 0 scans id1 -> rp1, block 1 scans id2 -> rp2.
__global__ void scan_kernel(const int* __restrict__ id1, const int* __restrict__ id2,
                            int* rp1, int* rp2) {
  const int* deg = blockIdx.x ? id2 : id1;
  int* rp = blockIdx.x ? rp2 : rp1;
  __shared__ int sm[1024];
  __shared__ int carry;
  int t = threadIdx.x;
  if (t == 0) carry = 0;
  __syncthreads();
  for (int base = 0; base < NN; base += 1024) {
    int v = (base + t < NN) ? deg[base + t] : 0;
    sm[t] = v;
    __syncthreads();
    #pragma unroll
    for (int o = 1; o < 1024; o <<= 1) {
      int add = (t >= o) ? sm[t - o] : 0;
      __syncthreads();
      sm[t] += add;
      __syncthreads();
    }
    if (base + t < NN) rp[base + t] = carry + sm[t] - v;  // exclusive
    __syncthreads();
    if (t == 0) carry += sm[1023];
    __syncthreads();
  }
  if (t == 0) rp[NN] = carry;
}

// ---------------------------------------------------------------- CSR fill
__global__ void fill_kernel(const int* __restrict__ s1, const int* __restrict__ d1,
                            const int* __restrict__ s2, const int* __restrict__ d2,
                            const int* __restrict__ rp1, const int* __restrict__ rp2,
                            int* fill1, int* fill2, int* col1, int* col2) {
  int i = blockIdx.x * blockDim.x + threadIdx.x;
  int st = gridDim.x * blockDim.x;
  for (int e = i; e < NE; e += st) {
    int sa = s1[e], da = d1[e], sb = s2[e], db = d2[e];
    int pa = atomicAdd(&fill1[da], 1);
    int pb = atomicAdd(&fill2[db], 1);
    col1[rp1[da] + pa] = sa;
    col2[rp2[db] + pb] = sb;
  }
}

// ---------------------------------------------------------------- SpMM gather
// One wave (64 lanes) per destination node. agg[dst] = inv_in[dst] *
// sum_{src in N(dst)} inv_out[src] * x[src, :].  F % 4 == 0.
template <int F>
__global__ __launch_bounds__(256) void spmm_kernel(
    const float* __restrict__ x, const int* __restrict__ rp, const int* __restrict__ col,
    const float* __restrict__ inv_out, const float* __restrict__ inv_in,
    float* __restrict__ outbuf) {
  constexpr int F4 = F / 4;
  constexpr int NI = (F4 + 63) / 64;
  int gw = (blockIdx.x * blockDim.x + threadIdx.x) >> 6;
  int lane = threadIdx.x & 63;
  int nw = (gridDim.x * blockDim.x) >> 6;
  const float4* __restrict__ x4 = (const float4*)x;
  float4* __restrict__ o4 = (float4*)outbuf;
  for (int node = gw; node < NN; node += nw) {
    float4 acc[NI];
    #pragma unroll
    for (int i = 0; i < NI; ++i) acc[i] = make_float4(0.f, 0.f, 0.f, 0.f);
    int beg = rp[node], end = rp[node + 1];
    for (int j = beg; j < end; ++j) {
      int s = col[j];
      float w = inv_out[s];
      #pragma unroll
      for (int i = 0; i < NI; ++i) {
        int idx = i * 64 + lane;
        if (idx < F4) {
          float4 v = x4[(size_t)s * F4 + idx];
          acc[i].x += v.x * w;
          acc[i].y += v.y * w;
          acc[i].z += v.z * w;
          acc[i].w += v.w * w;
        }
      }
    }
    float wi = inv_in[node];
    #pragma unroll
    for (int i = 0; i < NI; ++i) {
      int idx = i * 64 + lane;
      if (idx < F4) {
        float4 v = acc[i];
        v.x *= wi; v.y *= wi; v.z *= wi; v.w *= wi;
        o4[(size_t)node * F4 + idx] = v;
      }
    }
  }
}

// ---------------------------------------------------------------- GEMM (fp32)
// out[M,Nc] = epilogue(A[M,K] @ W[K,Nc] + bias, T)
// EPI 0: leaky(acc+bias)           -> out
// EPI 1: leaky(acc+bias) + T       -> out
// EPI 2: acc+bias                  -> out
// EPI 3: acc+bias + T              -> out
#define BM 128
#define BN 128
#define BK 20
#define LDA (BM + 4)
#define LDB (BN + 4)

template <int EPI>
__global__ __launch_bounds__(256, 2) void gemm_kernel(
    const float* __restrict__ A, const float* __restrict__ W,
    const float* __restrict__ bias, const float* __restrict__ T,
    float* __restrict__ out, int M, int K, int Nc) {
  __shared__ float As[BK * LDA];
  __shared__ float Bs[BK * LDB];
  const int tid = threadIdx.x;
  const int tx = tid & 15;
  const int ty = tid >> 4;
  const int m0 = blockIdx.y * BM;
  const int n0 = blockIdx.x * BN;

  float acc[2][2][4][4];
  #pragma unroll
  for (int i = 0; i < 2; ++i)
    #pragma unroll
    for (int j = 0; j < 2; ++j)
      #pragma unroll
      for (int a = 0; a < 4; ++a)
        #pragma unroll
        for (int b = 0; b < 4; ++b) acc[i][j][a][b] = 0.f;

  for (int k0 = 0; k0 < K; k0 += BK) {
    #pragma unroll
    for (int l = 0; l < 10; ++l) {  // A tile: 128x20
      int lin = l * 256 + tid;
      int r = lin / BK;
      int c = lin - r * BK;
      int gr = m0 + r;
      As[c * LDA + r] = (gr < M) ? A[(size_t)gr * K + (k0 + c)] : 0.f;
    }
    #pragma unroll
    for (int l = 0; l < 10; ++l) {  // B tile: 20x128
      int lin = l * 256 + tid;
      int kk = lin >> 7;
      int n = lin & 127;
      int gn = n0 + n;
      Bs[kk * LDB + n] = (gn < Nc) ? W[(size_t)(k0 + kk) * Nc + gn] : 0.f;
    }
    __syncthreads();
    #pragma unroll
    for (int kk = 0; kk < BK; ++kk) {
      float4 a0 = *(const float4*)&As[kk * LDA + ty * 4];
      float4 a1 = *(const float4*)&As[kk * LDA + 64 + ty * 4];
      float4 b0 = *(const float4*)&Bs[kk * LDB + tx * 4];
      float4 b1 = *(const float4*)&Bs[kk * LDB + 64 + tx * 4];
      float ar[2][4] = {{a0.x, a0.y, a0.z, a0.w}, {a1.x, a1.y, a1.z, a1.w}};
      float br[2][4] = {{b0.x, b0.y, b0.z, b0.w}, {b1.x, b1.y, b1.z, b1.w}};
      #pragma unroll
      for (int i = 0; i < 2; ++i)
        #pragma unroll
        for (int a = 0; a < 4; ++a)
          #pragma unroll
          for (int j = 0; j < 2; ++j)
            #pragma unroll
            for (int b = 0; b < 4; ++b)
              acc[i][j][a][b] += ar[i][a] * br[j][b];
    }
    __syncthreads();
  }

  #pragma unroll
  for (int i = 0; i < 2; ++i) {
    #pragma unroll
    for (int a = 0; a < 4; ++a) {
      int r = m0 + i * 64 + ty * 4 + a;
      if (r >= M) continue;
      #pragma unroll
      for (int j = 0; j < 2; ++j) {
        int c = n0 + j * 64 + tx * 4;
        if (c >= Nc) continue;  // Nc % 4 == 0, c % 4 == 0 -> full float4 valid
        float4 bi = *(const float4*)&bias[c];
        float v0 = acc[i][j][a][0] + bi.x;
        float v1 = acc[i][j][a][1] + bi.y;
        float v2 = acc[i][j][a][2] + bi.z;
        float v3 = acc[i][j][a][3] + bi.w;
        if (EPI == 0 || EPI == 1) {
          v0 = v0 > 0.f ? v0 : LEAKY * v0;
          v1 = v1 > 0.f ? v1 : LEAKY * v1;
          v2 = v2 > 0.f ? v2 : LEAKY * v2;
          v3 = v3 > 0.f ? v3 : LEAKY * v3;
        }
        if (EPI == 1 || EPI == 3) {
          float4 t = *(const float4*)&T[(size_t)r * Nc + c];
          v0 += t.x; v1 += t.y; v2 += t.z; v3 += t.w;
        }
        float4 o; o.x = v0; o.y = v1; o.z = v2; o.w = v3;
        *(float4*)&out[(size_t)r * Nc + c] = o;
      }
    }
  }
}

// ---------------------------------------------------------------- launch
extern "C" void kernel_launch(void* const* d_in, const int* in_sizes, int n_in,
                              void* d_out, int out_size, void* d_ws, size_t ws_size,
                              hipStream_t stream) {
  const float* emb = (const float*)d_in[0];
  const float* Wa1 = (const float*)d_in[1];
  const float* ba1 = (const float*)d_in[2];
  const float* Wa2 = (const float*)d_in[3];
  const float* ba2 = (const float*)d_in[4];
  const float* Wb1 = (const float*)d_in[5];
  const float* bb1 = (const float*)d_in[6];
  const float* Wb2 = (const float*)d_in[7];
  const float* bb2 = (const float*)d_in[8];
  const int* src1 = (const int*)d_in[9];
  const int* dst1 = (const int*)d_in[10];
  const int* src2 = (const int*)d_in[11];
  const int* dst2 = (const int*)d_in[12];
  float* out = (float*)d_out;

  char* ws = (char*)d_ws;
  size_t off = 0;
  auto alloc = [&](size_t nbytes) -> void* {
    off = (off + 255) & ~(size_t)255;
    void* p = ws + off;
    off += nbytes;
    return p;
  };
  int* od1 = (int*)alloc(NN * 4);
  int* id1 = (int*)alloc(NN * 4);
  int* od2 = (int*)alloc(NN * 4);
  int* id2 = (int*)alloc(NN * 4);
  int* fill1 = (int*)alloc(NN * 4);
  int* fill2 = (int*)alloc(NN * 4);
  int* rp1 = (int*)alloc((NN + 1) * 4);
  int* rp2 = (int*)alloc((NN + 1) * 4);
  int* col1 = (int*)alloc((size_t)NE * 4);
  int* col2 = (int*)alloc((size_t)NE * 4);
  float* io1 = (float*)alloc(NN * 4);
  float* ii1 = (float*)alloc(NN * 4);
  float* io2 = (float*)alloc(NN * 4);
  float* ii2 = (float*)alloc(NN * 4);
  float* bufA = (float*)alloc((size_t)NN * 400 * 4);  // agg buffer (300N or 400N used)
  float* bufT = (float*)alloc((size_t)NN * 512 * 4);  // gemm partial buffer
  float* X = (float*)d_out;  // hop-1 output [NN x 400] lives in d_out until final GEMM

  // zero the int count arrays (od1..fill2 region, incl. alignment padding)
  int nz = (int)(((char*)fill2 - (char*)od1) / 4) + NN;
  zero_ints<<<256, 256, 0, stream>>>(od1, nz);

  deg_kernel<<<1024, 256, 0, stream>>>(src1, dst1, src2, dst2, od1, id1, od2, id2);
  scale_kernel<<<(NN + 255) / 256, 256, 0, stream>>>(od1, id1, od2, id2, io1, ii1, io2, ii2);
  scan_kernel<<<2, 1024, 0, stream>>>(id1, id2, rp1, rp2);
  fill_kernel<<<1024, 256, 0, stream>>>(src1, dst1, src2, dst2, rp1, rp2,
                                        fill1, fill2, col1, col2);

  dim3 g1((400 + BN - 1) / BN, (NN + BM - 1) / BM);
  dim3 g2((512 + BN - 1) / BN, (NN + BM - 1) / BM);

  // hop 1
  spmm_kernel<300><<<12500, 256, 0, stream>>>(emb, rp1, col1, io1, ii1, bufA);
  gemm_kernel<0><<<g1, 256, 0, stream>>>(bufA, Wa1, ba1, (const float*)nullptr, bufT, NN, 300, 400);
  spmm_kernel<300><<<12500, 256, 0, stream>>>(emb, rp2, col2, io2, ii2, bufA);
  gemm_kernel<1><<<g1, 256, 0, stream>>>(bufA, Wb1, bb1, bufT, X, NN, 300, 400);

  // hop 2 (X read from d_out; final GEMM overwrites d_out after X is consumed)
  spmm_kernel<400><<<12500, 256, 0, stream>>>(X, rp1, col1, io1, ii1, bufA);
  gemm_kernel<2><<<g2, 256, 0, stream>>>(bufA, Wa2, ba2, (const float*)nullptr, bufT, NN, 400, 512);
  spmm_kernel<400><<<12500, 256, 0, stream>>>(X, rp2, col2, io2, ii2, bufA);
  gemm_kernel<3><<<g2, 256, 0, stream>>>(bufA, Wb2, bb2, bufT, out, NN, 400, 512);
}

// Round 4
// 1734.295 us; speedup vs baseline: 1.8422x; 1.8422x over previous
//
#include <hip/hip_runtime.h>

#define NN 50000
#define NE 800000
#define LEAKY 0.2f

using bf16x8 = __attribute__((ext_vector_type(8))) short;
using f32x4  = __attribute__((ext_vector_type(4))) float;

static __device__ __forceinline__ unsigned short f2bf(float f) {
  unsigned u = __float_as_uint(f);
  u += 0x7FFF + ((u >> 16) & 1);  // round-to-nearest-even
  return (unsigned short)(u >> 16);
}
static __device__ __forceinline__ float bf2f(unsigned short h) {
  return __uint_as_float((unsigned)h << 16);
}

// ---------------------------------------------------------------- zero
__global__ void zero_ints(int* __restrict__ p, int n) {
  int i = blockIdx.x * blockDim.x + threadIdx.x;
  int s = gridDim.x * blockDim.x;
  for (; i < n; i += s) p[i] = 0;
}

// ---------------------------------------------------------------- degrees
__global__ void deg_kernel(const int* __restrict__ s1, const int* __restrict__ d1,
                           const int* __restrict__ s2, const int* __restrict__ d2,
                           int* od1, int* id1, int* od2, int* id2) {
  int i = blockIdx.x * blockDim.x + threadIdx.x;
  int st = gridDim.x * blockDim.x;
  for (int e = i; e < NE; e += st) {
    int a = s1[e], b = d1[e], c = s2[e], d = d2[e];
    atomicAdd(&od1[a], 1);
    atomicAdd(&id1[b], 1);
    atomicAdd(&od2[c], 1);
    atomicAdd(&id2[d], 1);
  }
}

__global__ void scale_kernel(const int* __restrict__ od1, const int* __restrict__ id1,
                             const int* __restrict__ od2, const int* __restrict__ id2,
                             float* io1, float* ii1, float* io2, float* ii2) {
  int i = blockIdx.x * blockDim.x + threadIdx.x;
  if (i < NN) {
    io1[i] = rsqrtf((float)(od1[i] > 0 ? od1[i] : 1));
    ii1[i] = rsqrtf((float)(id1[i] > 0 ? id1[i] : 1));
    io2[i] = rsqrtf((float)(od2[i] > 0 ? od2[i] : 1));
    ii2[i] = rsqrtf((float)(id2[i] > 0 ? id2[i] : 1));
  }
}

// ---------------------------------------------------------------- scan (row_ptr)
__global__ void scan_kernel(const int* __restrict__ id1, const int* __restrict__ id2,
                            int* rp1, int* rp2) {
  const int* deg = blockIdx.x ? id2 : id1;
  int* rp = blockIdx.x ? rp2 : rp1;
  __shared__ int sm[1024];
  __shared__ int carry;
  int t = threadIdx.x;
  if (t == 0) carry = 0;
  __syncthreads();
  for (int base = 0; base < NN; base += 1024) {
    int v = (base + t < NN) ? deg[base + t] : 0;
    sm[t] = v;
    __syncthreads();
    #pragma unroll
    for (int o = 1; o < 1024; o <<= 1) {
      int add = (t >= o) ? sm[t - o] : 0;
      __syncthreads();
      sm[t] += add;
      __syncthreads();
    }
    if (base + t < NN) rp[base + t] = carry + sm[t] - v;  // exclusive
    __syncthreads();
    if (t == 0) carry += sm[1023];
    __syncthreads();
  }
  if (t == 0) rp[NN] = carry;
}

// ---------------------------------------------------------------- CSR fill
__global__ void fill_kernel(const int* __restrict__ s1, const int* __restrict__ d1,
                            const int* __restrict__ s2, const int* __restrict__ d2,
                            const int* __restrict__ rp1, const int* __restrict__ rp2,
                            int* fill1, int* fill2, int* col1, int* col2) {
  int i = blockIdx.x * blockDim.x + threadIdx.x;
  int st = gridDim.x * blockDim.x;
  for (int e = i; e < NE; e += st) {
    int sa = s1[e], da = d1[e], sb = s2[e], db = d2[e];
    int pa = atomicAdd(&fill1[da], 1);
    int pb = atomicAdd(&fill2[db], 1);
    col1[rp1[da] + pa] = sa;
    col2[rp2[db] + pb] = sb;
  }
}

// ---------------------------------------------------------------- SpMM gather
template <int F>
__global__ __launch_bounds__(256) void spmm_kernel(
    const float* __restrict__ x, const int* __restrict__ rp, const int* __restrict__ col,
    const float* __restrict__ inv_out, const float* __restrict__ inv_in,
    float* __restrict__ outbuf) {
  constexpr int F4 = F / 4;
  constexpr int NI = (F4 + 63) / 64;
  int gw = (blockIdx.x * blockDim.x + threadIdx.x) >> 6;
  int lane = threadIdx.x & 63;
  int nw = (gridDim.x * blockDim.x) >> 6;
  const float4* __restrict__ x4 = (const float4*)x;
  float4* __restrict__ o4 = (float4*)outbuf;
  for (int node = gw; node < NN; node += nw) {
    float4 acc[NI];
    #pragma unroll
    for (int i = 0; i < NI; ++i) acc[i] = make_float4(0.f, 0.f, 0.f, 0.f);
    int beg = rp[node], end = rp[node + 1];
    for (int j = beg; j < end; ++j) {
      int s = col[j];
      float w = inv_out[s];
      #pragma unroll
      for (int i = 0; i < NI; ++i) {
        int idx = i * 64 + lane;
        if (idx < F4) {
          float4 v = x4[(size_t)s * F4 + idx];
          acc[i].x += v.x * w;
          acc[i].y += v.y * w;
          acc[i].z += v.z * w;
          acc[i].w += v.w * w;
        }
      }
    }
    float wi = inv_in[node];
    #pragma unroll
    for (int i = 0; i < NI; ++i) {
      int idx = i * 64 + lane;
      if (idx < F4) {
        float4 v = acc[i];
        v.x *= wi; v.y *= wi; v.z *= wi; v.w *= wi;
        o4[(size_t)node * F4 + idx] = v;
      }
    }
  }
}

// ---------------------------------------------------------------- W pre-split
// W [K][Nc] fp32 -> Wh/Wl bf16 in fragment order: [nb(4)][kb(KB)][n(128)][k(32)],
// zero-padded outside (Nc, K).
__global__ void wsplit(const float* __restrict__ W, short* __restrict__ Wh,
                       short* __restrict__ Wl, int K, int Nc, int KB) {
  int total = 4 * KB * 4096;
  int i = blockIdx.x * blockDim.x + threadIdx.x;
  int st = gridDim.x * blockDim.x;
  for (; i < total; i += st) {
    int chunk = i >> 12;       // nb*KB + kb
    int e = i & 4095;
    int kk = e >> 7;           // 0..31
    int rn = e & 127;          // 0..127  (fast index -> coalesced W read)
    int nb = chunk / KB;
    int kb = chunk - nb * KB;
    int n = nb * 128 + rn;
    int k = kb * 32 + kk;
    float v = (n < Nc && k < K) ? W[(size_t)k * Nc + n] : 0.f;
    unsigned short h = f2bf(v);
    unsigned short l = f2bf(v - bf2f(h));
    size_t o = ((size_t)chunk * 128 + rn) * 32 + kk;
    Wh[o] = (short)h;
    Wl[o] = (short)l;
  }
}

// ---------------------------------------------------------------- MFMA GEMM (split-bf16)
// out[M,Nc] = epilogue(A1@W1 (+ A2@W2 if DUAL) + b1 (+ b2 if DUAL))
// EPI 0: leaky(v)          EPI 1: leaky(v) + T (in-place T==out is safe)
// EPI 2: v (plain)
// 128x128 tile, BK=32, 4 waves (2x2 of 64x64), 3 MFMAs per frag pair (hh,hl,lh).
// LDS tiles padded to 40-short rows (80B stride) -> uniform bank use for b128.
template <int EPI, int DUAL>
__global__ __launch_bounds__(256, 2) void mgemm(
    const float* __restrict__ A1, const float* __restrict__ A2,
    const short* __restrict__ W1h, const short* __restrict__ W1l,
    const short* __restrict__ W2h, const short* __restrict__ W2l,
    const float* __restrict__ b1, const float* __restrict__ b2,
    const float* __restrict__ T, float* __restrict__ out,
    int M, int K, int Nc, int KB) {
  __shared__ short Ah[128 * 40];
  __shared__ short Al[128 * 40];
  __shared__ short Bh[128 * 40];
  __shared__ short Bl[128 * 40];

  const int tid = threadIdx.x;
  const int m0 = blockIdx.y * 128;
  const int nb = blockIdx.x;
  const int n0 = nb * 128;

  const int lane = tid & 63;
  const int wid = tid >> 6;
  const int wr = (wid >> 1) * 64;  // wave row offset in tile
  const int wc = (wid & 1) * 64;   // wave col offset in tile
  const int lr = lane & 15;
  const int lk = (lane >> 4) * 8;  // k element offset for frag b128 read

  f32x4 acc[4][4];
  #pragma unroll
  for (int i = 0; i < 4; ++i)
    #pragma unroll
    for (int j = 0; j < 4; ++j) acc[i][j] = (f32x4)(0.f);

  const int sr = tid >> 1;          // staging: A/B row 0..127
  const int sk = (tid & 1) * 16;    // staging: k half

  for (int kb = 0; kb < KB; ++kb) {
    // ======== chain 1: stage ========
    {
      const float* arow = A1 + (size_t)(m0 + sr) * K + kb * 32 + sk;
      bool rok = (m0 + sr) < M;
      #pragma unroll
      for (int i4 = 0; i4 < 4; ++i4) {
        int kg = kb * 32 + sk + i4 * 4;
        float4 v = make_float4(0.f, 0.f, 0.f, 0.f);
        if (rok && kg + 4 <= K) v = *(const float4*)(arow + i4 * 4);
        unsigned short hx = f2bf(v.x), hy = f2bf(v.y), hz = f2bf(v.z), hw = f2bf(v.w);
        short4 h = make_short4((short)hx, (short)hy, (short)hz, (short)hw);
        short4 l = make_short4((short)f2bf(v.x - bf2f(hx)), (short)f2bf(v.y - bf2f(hy)),
                               (short)f2bf(v.z - bf2f(hz)), (short)f2bf(v.w - bf2f(hw)));
        *(short4*)&Ah[sr * 40 + sk + i4 * 4] = h;
        *(short4*)&Al[sr * 40 + sk + i4 * 4] = l;
      }
      size_t wbase = (((size_t)nb * KB + kb) << 12) + sr * 32 + sk;
      const uint4* sh = (const uint4*)(W1h + wbase);
      const uint4* sl = (const uint4*)(W1l + wbase);
      *(uint4*)&Bh[sr * 40 + sk]     = sh[0];
      *(uint4*)&Bh[sr * 40 + sk + 8] = sh[1];
      *(uint4*)&Bl[sr * 40 + sk]     = sl[0];
      *(uint4*)&Bl[sr * 40 + sk + 8] = sl[1];
    }
    __syncthreads();
    // ======== chain 1: compute ========
    {
      bf16x8 fah[4], fal[4], fbh[4], fbl[4];
      #pragma unroll
      for (int i = 0; i < 4; ++i) {
        fah[i] = *(const bf16x8*)&Ah[(wr + i * 16 + lr) * 40 + lk];
        fal[i] = *(const bf16x8*)&Al[(wr + i * 16 + lr) * 40 + lk];
      }
      #pragma unroll
      for (int j = 0; j < 4; ++j) {
        fbh[j] = *(const bf16x8*)&Bh[(wc + j * 16 + lr) * 40 + lk];
        fbl[j] = *(const bf16x8*)&Bl[(wc + j * 16 + lr) * 40 + lk];
      }
      #pragma unroll
      for (int i = 0; i < 4; ++i)
        #pragma unroll
        for (int j = 0; j < 4; ++j) {
          acc[i][j] = __builtin_amdgcn_mfma_f32_16x16x32_bf16(fah[i], fbh[j], acc[i][j], 0, 0, 0);
          acc[i][j] = __builtin_amdgcn_mfma_f32_16x16x32_bf16(fah[i], fbl[j], acc[i][j], 0, 0, 0);
          acc[i][j] = __builtin_amdgcn_mfma_f32_16x16x32_bf16(fal[i], fbh[j], acc[i][j], 0, 0, 0);
        }
    }
    __syncthreads();
    if (DUAL) {
      // ======== chain 2: stage ========
      {
        const float* arow = A2 + (size_t)(m0 + sr) * K + kb * 32 + sk;
        bool rok = (m0 + sr) < M;
        #pragma unroll
        for (int i4 = 0; i4 < 4; ++i4) {
          int kg = kb * 32 + sk + i4 * 4;
          float4 v = make_float4(0.f, 0.f, 0.f, 0.f);
          if (rok && kg + 4 <= K) v = *(const float4*)(arow + i4 * 4);
          unsigned short hx = f2bf(v.x), hy = f2bf(v.y), hz = f2bf(v.z), hw = f2bf(v.w);
          short4 h = make_short4((short)hx, (short)hy, (short)hz, (short)hw);
          short4 l = make_short4((short)f2bf(v.x - bf2f(hx)), (short)f2bf(v.y - bf2f(hy)),
                                 (short)f2bf(v.z - bf2f(hz)), (short)f2bf(v.w - bf2f(hw)));
          *(short4*)&Ah[sr * 40 + sk + i4 * 4] = h;
          *(short4*)&Al[sr * 40 + sk + i4 * 4] = l;
        }
        size_t wbase = (((size_t)nb * KB + kb) << 12) + sr * 32 + sk;
        const uint4* sh = (const uint4*)(W2h + wbase);
        const uint4* sl = (const uint4*)(W2l + wbase);
        *(uint4*)&Bh[sr * 40 + sk]     = sh[0];
        *(uint4*)&Bh[sr * 40 + sk + 8] = sh[1];
        *(uint4*)&Bl[sr * 40 + sk]     = sl[0];
        *(uint4*)&Bl[sr * 40 + sk + 8] = sl[1];
      }
      __syncthreads();
      // ======== chain 2: compute ========
      {
        bf16x8 fah[4], fal[4], fbh[4], fbl[4];
        #pragma unroll
        for (int i = 0; i < 4; ++i) {
          fah[i] = *(const bf16x8*)&Ah[(wr + i * 16 + lr) * 40 + lk];
          fal[i] = *(const bf16x8*)&Al[(wr + i * 16 + lr) * 40 + lk];
        }
        #pragma unroll
        for (int j = 0; j < 4; ++j) {
          fbh[j] = *(const bf16x8*)&Bh[(wc + j * 16 + lr) * 40 + lk];
          fbl[j] = *(const bf16x8*)&Bl[(wc + j * 16 + lr) * 40 + lk];
        }
        #pragma unroll
        for (int i = 0; i < 4; ++i)
          #pragma unroll
          for (int j = 0; j < 4; ++j) {
            acc[i][j] = __builtin_amdgcn_mfma_f32_16x16x32_bf16(fah[i], fbh[j], acc[i][j], 0, 0, 0);
            acc[i][j] = __builtin_amdgcn_mfma_f32_16x16x32_bf16(fah[i], fbl[j], acc[i][j], 0, 0, 0);
            acc[i][j] = __builtin_amdgcn_mfma_f32_16x16x32_bf16(fal[i], fbh[j], acc[i][j], 0, 0, 0);
          }
      }
      __syncthreads();
    }
  }

  // ======== epilogue ========
  // C/D layout (m89-verified): col = lane&15, row = (lane>>4)*4 + reg
  #pragma unroll
  for (int i = 0; i < 4; ++i) {
    #pragma unroll
    for (int rr = 0; rr < 4; ++rr) {
      int r = m0 + wr + i * 16 + (lane >> 4) * 4 + rr;
      if (r >= M) continue;
      #pragma unroll
      for (int j = 0; j < 4; ++j) {
        int c = n0 + wc + j * 16 + lr;
        if (c >= Nc) continue;
        float v = acc[i][j][rr] + b1[c];
        if (DUAL) v += b2[c];
        if (EPI == 0 || EPI == 1) v = v > 0.f ? v : LEAKY * v;
        if (EPI == 1) v += T[(size_t)r * Nc + c];
        out[(size_t)r * Nc + c] = v;
      }
    }
  }
}

// ---------------------------------------------------------------- launch
extern "C" void kernel_launch(void* const* d_in, const int* in_sizes, int n_in,
                              void* d_out, int out_size, void* d_ws, size_t ws_size,
                              hipStream_t stream) {
  const float* emb = (const float*)d_in[0];
  const float* Wa1 = (const float*)d_in[1];
  const float* ba1 = (const float*)d_in[2];
  const float* Wa2 = (const float*)d_in[3];
  const float* ba2 = (const float*)d_in[4];
  const float* Wb1 = (const float*)d_in[5];
  const float* bb1 = (const float*)d_in[6];
  const float* Wb2 = (const float*)d_in[7];
  const float* bb2 = (const float*)d_in[8];
  const int* src1 = (const int*)d_in[9];
  const int* dst1 = (const int*)d_in[10];
  const int* src2 = (const int*)d_in[11];
  const int* dst2 = (const int*)d_in[12];
  float* out = (float*)d_out;

  char* ws = (char*)d_ws;
  size_t off = 0;
  auto alloc = [&](size_t nbytes) -> void* {
    off = (off + 255) & ~(size_t)255;
    void* p = ws + off;
    off += nbytes;
    return p;
  };
  int* od1 = (int*)alloc(NN * 4);
  int* id1 = (int*)alloc(NN * 4);
  int* od2 = (int*)alloc(NN * 4);
  int* id2 = (int*)alloc(NN * 4);
  int* fill1 = (int*)alloc(NN * 4);
  int* fill2 = (int*)alloc(NN * 4);
  int* rp1 = (int*)alloc((NN + 1) * 4);
  int* rp2 = (int*)alloc((NN + 1) * 4);
  int* col1 = (int*)alloc((size_t)NE * 4);
  int* col2 = (int*)alloc((size_t)NE * 4);
  float* io1 = (float*)alloc(NN * 4);
  float* ii1 = (float*)alloc(NN * 4);
  float* io2 = (float*)alloc(NN * 4);
  float* ii2 = (float*)alloc(NN * 4);
  const int KB1 = 10;  // ceil(300/32)
  const int KB2 = 13;  // ceil(400/32)
  short* Wa1h = (short*)alloc((size_t)4 * KB1 * 4096 * 2);
  short* Wa1l = (short*)alloc((size_t)4 * KB1 * 4096 * 2);
  short* Wb1h = (short*)alloc((size_t)4 * KB1 * 4096 * 2);
  short* Wb1l = (short*)alloc((size_t)4 * KB1 * 4096 * 2);
  short* Wa2h = (short*)alloc((size_t)4 * KB2 * 4096 * 2);
  short* Wa2l = (short*)alloc((size_t)4 * KB2 * 4096 * 2);
  short* Wb2h = (short*)alloc((size_t)4 * KB2 * 4096 * 2);
  short* Wb2l = (short*)alloc((size_t)4 * KB2 * 4096 * 2);
  float* bufA1 = (float*)alloc((size_t)NN * 400 * 4);
  float* bufA2 = (float*)alloc((size_t)NN * 400 * 4);
  float* X = (float*)d_out;  // hop-1 intermediate + T live in d_out (cols < 400)

  int nz = (int)(((char*)fill2 - (char*)od1) / 4) + NN;
  zero_ints<<<256, 256, 0, stream>>>(od1, nz);

  deg_kernel<<<1024, 256, 0, stream>>>(src1, dst1, src2, dst2, od1, id1, od2, id2);
  scale_kernel<<<(NN + 255) / 256, 256, 0, stream>>>(od1, id1, od2, id2, io1, ii1, io2, ii2);
  scan_kernel<<<2, 1024, 0, stream>>>(id1, id2, rp1, rp2);
  fill_kernel<<<1024, 256, 0, stream>>>(src1, dst1, src2, dst2, rp1, rp2,
                                        fill1, fill2, col1, col2);

  wsplit<<<640, 256, 0, stream>>>(Wa1, Wa1h, Wa1l, 300, 400, KB1);
  wsplit<<<640, 256, 0, stream>>>(Wb1, Wb1h, Wb1l, 300, 400, KB1);
  wsplit<<<832, 256, 0, stream>>>(Wa2, Wa2h, Wa2l, 400, 512, KB2);
  wsplit<<<832, 256, 0, stream>>>(Wb2, Wb2h, Wb2l, 400, 512, KB2);

  dim3 gg(4, (NN + 127) / 128);  // 4 x 391

  // hop 1: x = leaky(gcn1) + leaky(gcn2), parked in d_out[:, :400]
  spmm_kernel<300><<<12500, 256, 0, stream>>>(emb, rp1, col1, io1, ii1, bufA1);
  mgemm<0, 0><<<gg, 256, 0, stream>>>(bufA1, nullptr, Wa1h, Wa1l, nullptr, nullptr,
                                      ba1, nullptr, nullptr, X, NN, 300, 400, KB1);
  spmm_kernel<300><<<12500, 256, 0, stream>>>(emb, rp2, col2, io2, ii2, bufA2);
  mgemm<1, 0><<<gg, 256, 0, stream>>>(bufA2, nullptr, Wb1h, Wb1l, nullptr, nullptr,
                                      bb1, nullptr, X, X, NN, 300, 400, KB1);

  // hop 2: y = agg1@Wa2 + agg2@Wb2 + ba2 + bb2 (fused dual-chain GEMM)
  spmm_kernel<400><<<12500, 256, 0, stream>>>(X, rp1, col1, io1, ii1, bufA1);
  spmm_kernel<400><<<12500, 256, 0, stream>>>(X, rp2, col2, io2, ii2, bufA2);
  mgemm<2, 1><<<gg, 256, 0, stream>>>(bufA1, bufA2, Wa2h, Wa2l, Wb2h, Wb2l,
                                      ba2, bb2, nullptr, out, NN, 400, 512, KB2);
}